// Round 4
// baseline (493.344 us; speedup 1.0000x reference)
//
#include <hip/hip_runtime.h>
#include <cstdint>
#include <cstddef>

typedef float f32x4 __attribute__((ext_vector_type(4)));
typedef __bf16 bf16x8_t __attribute__((ext_vector_type(8)));
typedef short s16x8_t __attribute__((ext_vector_type(8)));
typedef unsigned short u16x4_t __attribute__((ext_vector_type(4)));

#define NN 8192   // nodes
#define FD 512    // in features
#define HD 256    // hidden
#define CD 40    // classes

static __device__ __forceinline__ unsigned short f2bf(float f) {
    unsigned int u = __builtin_bit_cast(unsigned int, f);
    u += 0x7FFFu + ((u >> 16) & 1u);          // round-to-nearest-even
    return (unsigned short)(u >> 16);
}
static __device__ __forceinline__ float bf2f(unsigned short s) {
    unsigned int u = ((unsigned int)s) << 16;
    return __builtin_bit_cast(float, u);
}

typedef __attribute__((address_space(3))) unsigned int lds_u32_t;
typedef __attribute__((address_space(1))) const unsigned int gbl_u32_t;
static __device__ __forceinline__ void gload16(const void* g, const void* lds) {
    __builtin_amdgcn_global_load_lds((gbl_u32_t*)g, (lds_u32_t*)lds, 16, 0, 0);
}

// ---------------- K-1: zero the rowsum accumulators ----------------
__global__ __launch_bounds__(256) void k_zero(float* __restrict__ S1,
                                              float* __restrict__ S2) {
    const int i = blockIdx.x * 256 + threadIdx.x;
    S1[i] = 0.f;
    S2[i] = 0.f;
}

// ---------------- K1: sup1 = x @ w1  (8192x512 @ 512x256, f32 vector) ----------------
__global__ __launch_bounds__(256) void k_xw1(const float* __restrict__ x,
                                             const float* __restrict__ w1,
                                             float* __restrict__ sup1) {
    __shared__ float xs[64][36];
    __shared__ float ws[32][68];
    const int m0 = (blockIdx.x >> 2) * 64;
    const int n0 = (blockIdx.x & 3) * 64;
    const int t = threadIdx.x;
    const int tx = t & 15, ty = t >> 4;
    float acc[4][4] = {};
    for (int k0 = 0; k0 < FD; k0 += 32) {
        for (int i = t; i < 512; i += 256) {
            int r = i >> 3, c = (i & 7) << 2;
            *(float4*)&xs[r][c] = *(const float4*)&x[(size_t)(m0 + r) * FD + k0 + c];
        }
        for (int i = t; i < 512; i += 256) {
            int r = i >> 4, c = (i & 15) << 2;
            *(float4*)&ws[r][c] = *(const float4*)&w1[(size_t)(k0 + r) * HD + n0 + c];
        }
        __syncthreads();
        for (int k = 0; k < 32; ++k) {
            float a_[4], b_[4];
            #pragma unroll
            for (int i = 0; i < 4; ++i) a_[i] = xs[ty * 4 + i][k];
            #pragma unroll
            for (int j = 0; j < 4; ++j) b_[j] = ws[k][tx * 4 + j];
            #pragma unroll
            for (int i = 0; i < 4; ++i)
                #pragma unroll
                for (int j = 0; j < 4; ++j) acc[i][j] += a_[i] * b_[j];
        }
        __syncthreads();
    }
    #pragma unroll
    for (int i = 0; i < 4; ++i)
        #pragma unroll
        for (int j = 0; j < 4; ++j)
            sup1[(size_t)(m0 + ty * 4 + i) * HD + n0 + tx * 4 + j] = acc[i][j];
}

// ---------------- K2: pack B1T[n][k] (bf16, 320 x 8192) = [sup1 | y | 0-pad]^T ----------------
__global__ __launch_bounds__(256) void k_packB1T(const float* __restrict__ sup1,
                                                 const float* __restrict__ y,
                                                 unsigned short* __restrict__ B1T) {
    __shared__ float tl[64][33];
    const int kt = blockIdx.x & 127;
    const int nt = blockIdx.x >> 7;
    const int k0 = kt * 64, n0 = nt * 32;
    const int t = threadIdx.x;
    {
        const int kr = t >> 2, cb = (t & 3) * 8;
        #pragma unroll
        for (int j = 0; j < 8; ++j) {
            const int n = n0 + cb + j;
            float v;
            if (n < 256)      v = sup1[(size_t)(k0 + kr) * HD + n];
            else if (n < 296) v = y[(size_t)(k0 + kr) * CD + (n - 256)];
            else              v = 0.f;
            tl[kr][cb + j] = v;
        }
    }
    __syncthreads();
    {
        const int nr = t >> 3, part = t & 7;
        unsigned short tmp[8];
        #pragma unroll
        for (int j = 0; j < 8; ++j) tmp[j] = f2bf(tl[part * 8 + j][nr]);
        *(s16x8_t*)&B1T[(size_t)(n0 + nr) * NN + k0 + part * 8] = *(s16x8_t*)tmp;
    }
}

// ---------------- K3: fused GEMM: A = bf16(adj .* mask) computed in-staging ----------------
// Replaces the former k_prep + k_gemm pair: the elementwise product + bf16 convert happens
// in the A-staging path (reg-staged, same XOR-swizzled LDS layout as the gload_lds version),
// and row sums of |P| accumulate in registers -> one atomicAdd per row in the epilogue
// (GEMM1: nt==0 sibling only; GEMM2/NTILES==1: every block covers its K-slice exactly once).
// MFMA core / fragments / C-epilogue identical to the previously verified k_gemm.
// For NTILES>1: XCD-grouping block remap (r3, measured win) so A-panel siblings share L2.
template<int BN, int WM, int WN, int SPLIT, int NTILES>
__global__ __launch_bounds__(256) void k_gemmF(const float* __restrict__ adj,
                                               const float* __restrict__ mask,
                                               const unsigned short* __restrict__ Bt,
                                               float* __restrict__ Cp,
                                               float* __restrict__ S) {
    constexpr int BM = 128, BK = 64;
    constexpr int MF = BM / (WM * 16);
    constexpr int NF = BN / (WN * 16);
    constexpr int NBI = BN / 32;          // B gload insts per wave
    constexpr int NSTR = NTILES * BN;     // Cp row stride
    constexpr int MT = NN / BM;           // 64 m-tiles
    __shared__ unsigned short As[BM * BK];
    __shared__ unsigned short Bs[BN * BK];
    int mt, ks, nt;
    if constexpr (NTILES > 1) {
        constexpr int NXCD = 8;
        constexpr int PAIRS = MT * SPLIT;              // (mt,ks) pairs
        static_assert(PAIRS % NXCD == 0, "pair count must split across XCDs");
        constexpr int PPX = PAIRS / NXCD;              // pairs per XCD
        const int L = blockIdx.x;
        const int x = L % NXCD, q = L / NXCD;          // XCD id, slot on that XCD
        const int pr = x * PPX + q / NTILES;           // pair index
        nt = q % NTILES;
        mt = pr / SPLIT;
        ks = pr % SPLIT;
    } else {
        int b = blockIdx.x;
        nt = 0;
        ks = b % SPLIT;  b /= SPLIT;
        mt = b;
    }
    const int m0 = mt * BM, n0 = nt * BN;
    const int t = threadIdx.x, w = t >> 6, ln = t & 63;
    const int wn = w % WN, wm = w / WN;
    const int lrow = ln & 15, lkq = ln >> 4;
    const int kbeg = ks * (NN / SPLIT), kend = kbeg + (NN / SPLIT);
    const bool dosum = (NTILES == 1) || (nt == 0);

    // A-staging: granule g = t + i*256 (i<8) -> local row r = g>>4, q16 = g&15
    // (16 f32x4 granules per 64-col row). 16 lanes cover one row's 256B contiguously
    // per matrix -> fully coalesced. LDS target keeps the XOR chunk swizzle:
    // chunk cg = q16>>1 stored at slot cg^(r&7), half (q16&1).
    float rsum[8] = {};
    f32x4 acc[MF][NF] = {};
    for (int kb = kbeg; kb < kend; kb += BK) {
        f32x4 av[8], mv[8];
        #pragma unroll
        for (int i = 0; i < 8; ++i) {
            const int g = t + i * 256;
            const int r = g >> 4, q16 = g & 15;
            const size_t goff = (size_t)(m0 + r) * NN + kb + q16 * 4;
            av[i] = *(const f32x4*)&adj[goff];
            mv[i] = *(const f32x4*)&mask[goff];
        }
        // B stage (BN*128 bytes, direct-to-LDS)
        #pragma unroll
        for (int i = 0; i < NBI; ++i) {
            const int off = (w * NBI + i) * 1024 + ln * 16;
            const int r = off >> 7, ch = (off >> 4) & 7;
            gload16(Bt + (size_t)(n0 + r) * NN + kb + ((ch ^ (r & 7)) << 3),
                    &Bs[(w * NBI + i) * 512]);
        }
        f32x4 pr8[8];
        #pragma unroll
        for (int i = 0; i < 8; ++i) {
            #pragma unroll
            for (int e = 0; e < 4; ++e) pr8[i][e] = av[i][e] * mv[i][e];
        }
        if (dosum) {
            #pragma unroll
            for (int i = 0; i < 8; ++i)
                rsum[i] += fabsf(pr8[i][0]) + fabsf(pr8[i][1]) + fabsf(pr8[i][2]) + fabsf(pr8[i][3]);
        }
        #pragma unroll
        for (int i = 0; i < 8; ++i) {
            const int g = t + i * 256;
            const int r = g >> 4, q16 = g & 15;
            u16x4_t pk;
            pk.x = f2bf(pr8[i][0]); pk.y = f2bf(pr8[i][1]);
            pk.z = f2bf(pr8[i][2]); pk.w = f2bf(pr8[i][3]);
            *(u16x4_t*)&As[r * 64 + (((q16 >> 1) ^ (r & 7)) << 3) + ((q16 & 1) << 2)] = pk;
        }
        __syncthreads();   // drains vmcnt (gload_lds) + lgkmcnt (ds_write)

        bf16x8_t af[MF][2];
        #pragma unroll
        for (int mf = 0; mf < MF; ++mf)
            #pragma unroll
            for (int kh = 0; kh < 2; ++kh) {
                const int r = wm * (MF * 16) + mf * 16 + lrow;
                const int ch = (kh * 4 + lkq) ^ (r & 7);
                af[mf][kh] = __builtin_bit_cast(bf16x8_t, *(const s16x8_t*)&As[r * 64 + ch * 8]);
            }
        bf16x8_t bfr[NF][2];
        #pragma unroll
        for (int nf = 0; nf < NF; ++nf)
            #pragma unroll
            for (int kh = 0; kh < 2; ++kh) {
                const int r = wn * (NF * 16) + nf * 16 + lrow;
                const int ch = (kh * 4 + lkq) ^ (r & 7);
                bfr[nf][kh] = __builtin_bit_cast(bf16x8_t, *(const s16x8_t*)&Bs[r * 64 + ch * 8]);
            }
        #pragma unroll
        for (int kh = 0; kh < 2; ++kh)
            #pragma unroll
            for (int mf = 0; mf < MF; ++mf)
                #pragma unroll
                for (int nf = 0; nf < NF; ++nf)
                    acc[mf][nf] = __builtin_amdgcn_mfma_f32_16x16x32_bf16(
                        af[mf][kh], bfr[nf][kh], acc[mf][nf], 0, 0, 0);
        __syncthreads();
    }
    // epilogue: partial f32 store. C/D layout: col = lane&15 (from Bt row), row = (lane>>4)*4+e (from A row)
    #pragma unroll
    for (int mf = 0; mf < MF; ++mf)
        #pragma unroll
        for (int nf = 0; nf < NF; ++nf)
            #pragma unroll
            for (int e = 0; e < 4; ++e) {
                const int m = m0 + wm * (MF * 16) + mf * 16 + lkq * 4 + e;
                const int n = n0 + wn * (NF * 16) + nf * 16 + lrow;
                Cp[((size_t)ks * NN + m) * NSTR + n] = acc[mf][nf][e];
            }
    // rowsum commit: thread's granule rows are r(i) = w*4 + (ln>>4) + i*16;
    // 16 lanes (same ln>>4 group) share each row -> xor-reduce 1,2,4,8 then one atomic.
    if (dosum) {
        #pragma unroll
        for (int i = 0; i < 8; ++i) {
            float v = rsum[i];
            v += __shfl_xor(v, 1, 64);
            v += __shfl_xor(v, 2, 64);
            v += __shfl_xor(v, 4, 64);
            v += __shfl_xor(v, 8, 64);
            if ((ln & 15) == 0)
                atomicAdd(&S[m0 + w * 4 + (ln >> 4) + i * 16], v);
        }
    }
}

// ---------------- K4: finC — U1 = sum(Uc parts)/rowsum; h1 = relu(+b1) bf16; yh1 -> B2T rows 40..79 ----------------
__global__ __launch_bounds__(256) void k_finC(const float* __restrict__ U,   // [2][NN][320]
                                              const float* __restrict__ S1,  // raw rowsums
                                              const float* __restrict__ b1,
                                              unsigned short* __restrict__ h1,
                                              unsigned short* __restrict__ B2T) {
    const int t = threadIdx.x;
    const int r = t >> 3, l8 = t & 7;
    const int m = blockIdx.x * 32 + r;
    const float si = 1.0f / fmaxf(S1[m], 1e-12f);
    const float* __restrict__ u0 = U + (size_t)m * 320;
    const float* __restrict__ u1 = U + (size_t)(NN + m) * 320;
    #pragma unroll
    for (int i = 0; i < 10; ++i) {
        const int c = (l8 + i * 8) * 4;       // 0..316
        f32x4 a = *(const f32x4*)&u0[c];
        f32x4 b = *(const f32x4*)&u1[c];
        f32x4 v;
        #pragma unroll
        for (int e = 0; e < 4; ++e) v[e] = (a[e] + b[e]) * si;
        if (i < 8) {                           // c < 256: hidden part
            u16x4_t pk;
            #pragma unroll
            for (int e = 0; e < 4; ++e) {
                const float hv = fmaxf(v[e] + b1[c + e], 0.f);
                ((unsigned short*)&pk)[e] = f2bf(hv);
            }
            *(u16x4_t*)&h1[(size_t)m * HD + c] = pk;
        } else {                               // c in 256..316: y_hat part
            #pragma unroll
            for (int e = 0; e < 4; ++e) {
                const int cc = c + e;
                if (cc < 296) B2T[(size_t)(40 + cc - 256) * NN + m] = f2bf(v[e]);
            }
        }
    }
}

// ---------------- K5: support2 = h1 @ w2 -> B2T rows 0..39 (transposed bf16); zero rows 80..95 ----------------
__global__ __launch_bounds__(256) void k_hw2(const unsigned short* __restrict__ h1,
                                             const float* __restrict__ w2,
                                             unsigned short* __restrict__ B2T) {
    __shared__ float w2s[HD * CD];
    __shared__ unsigned short h1s[32][264];
    __shared__ float ot[CD][33];
    const int t = threadIdx.x;
    const int mb = blockIdx.x * 32;
    for (int i = t; i < HD * CD; i += 256) w2s[i] = w2[i];
    for (int i = t; i < 1024; i += 256) {
        const int r = i >> 5, c = (i & 31) * 8;
        *(s16x8_t*)&h1s[r][c] = *(const s16x8_t*)&h1[(size_t)(mb + r) * HD + c];
    }
    __syncthreads();
    const int m = t >> 3, n0 = t & 7;
    float a5[5] = {};
    for (int k = 0; k < HD; ++k) {
        const float hv = bf2f(h1s[m][k]);
        #pragma unroll
        for (int j = 0; j < 5; ++j) a5[j] += hv * w2s[k * CD + n0 + 8 * j];
    }
    #pragma unroll
    for (int j = 0; j < 5; ++j) ot[n0 + 8 * j][m] = a5[j];
    __syncthreads();
    for (int i = t; i < CD * 32; i += 256) {
        const int n = i >> 5, mm = i & 31;
        B2T[(size_t)n * NN + mb + mm] = f2bf(ot[n][mm]);
    }
    for (int i = t; i < 16 * 32; i += 256)    // zero pad rows 80..95
        B2T[(size_t)(80 + (i >> 5)) * NN + mb + (i & 31)] = 0;
}

// ---------------- K6: finD — sum 8 partials, /rowsum, +b2, log_softmax both mats, store ----------------
__global__ __launch_bounds__(256) void k_finD(const float* __restrict__ U,   // [8][NN][96]
                                              const float* __restrict__ S2,  // raw rowsums
                                              const float* __restrict__ b2,
                                              float* __restrict__ out) {
    __shared__ float vt[32][100];
    const int t = threadIdx.x;
    const int mb = blockIdx.x * 32;
    for (int i = t; i < 32 * 24; i += 256) {
        const int r = i / 24, f4 = i % 24;
        const int m = mb + r;
        f32x4 s = {};
        #pragma unroll
        for (int p = 0; p < 8; ++p) {
            f32x4 v = *(const f32x4*)&U[((size_t)p * NN + m) * 96 + f4 * 4];
            #pragma unroll
            for (int e = 0; e < 4; ++e) s[e] += v[e];
        }
        const float si = 1.0f / fmaxf(S2[m], 1e-12f);
        #pragma unroll
        for (int e = 0; e < 4; ++e) {
            const int c = f4 * 4 + e;
            float v = s[e] * si;
            if (c < CD) v += b2[c];
            vt[r][c] = v;
        }
    }
    __syncthreads();
    const int l8 = t & 7;
    #pragma unroll
    for (int pass = 0; pass < 2; ++pass) {
        const int task = pass * 32 + (t >> 3);
        const int row = task & 31, mat = task >> 5;
        float vals[5];
        float mx = -3.0e38f;
        #pragma unroll
        for (int j = 0; j < 5; ++j) { vals[j] = vt[row][mat * CD + l8 + 8 * j]; mx = fmaxf(mx, vals[j]); }
        mx = fmaxf(mx, __shfl_xor(mx, 4, 8));
        mx = fmaxf(mx, __shfl_xor(mx, 2, 8));
        mx = fmaxf(mx, __shfl_xor(mx, 1, 8));
        float se = 0.f;
        #pragma unroll
        for (int j = 0; j < 5; ++j) se += expf(vals[j] - mx);
        se += __shfl_xor(se, 4, 8);
        se += __shfl_xor(se, 2, 8);
        se += __shfl_xor(se, 1, 8);
        const float ls = logf(se);
        float* op = out + (size_t)mat * (NN * CD) + (size_t)(mb + row) * CD;
        #pragma unroll
        for (int j = 0; j < 5; ++j) op[l8 + 8 * j] = vals[j] - mx - ls;
    }
}

extern "C" void kernel_launch(void* const* d_in, const int* in_sizes, int n_in,
                              void* d_out, int out_size, void* d_ws, size_t ws_size,
                              hipStream_t stream) {
    (void)in_sizes; (void)n_in; (void)out_size; (void)ws_size;
    const float* x     = (const float*)d_in[0];
    const float* adj   = (const float*)d_in[1];
    const float* y     = (const float*)d_in[2];
    const float* mask1 = (const float*)d_in[3];
    const float* mask2 = (const float*)d_in[4];
    const float* w1    = (const float*)d_in[5];
    const float* b1    = (const float*)d_in[6];
    const float* w2    = (const float*)d_in[7];
    const float* b2    = (const float*)d_in[8];
    float* out = (float*)d_out;

    char* p = (char*)d_ws;
    float*          sup1 = (float*)p;          p += 8388608;    // 8192x256 f32
    unsigned short* B1T  = (unsigned short*)p; p += 5242880;    // 320x8192 bf16
    unsigned short* h1   = (unsigned short*)p; p += 4194304;    // 8192x256 bf16
    unsigned short* B2T  = (unsigned short*)p; p += 1572864;    // 96x8192 bf16
    float*          U    = (float*)p;          p += 25165824;   // overlay: Uc[2][8192][320] / Ud[8][8192][96]
    float*          S1   = (float*)p;          p += 32768;      // raw rowsums |adj.*mask1|
    float*          S2   = (float*)p;          p += 32768;      // raw rowsums |adj.*mask2|

    hipLaunchKernelGGL(k_zero,    dim3(32),   dim3(256), 0, stream, S1, S2);
    hipLaunchKernelGGL(k_xw1,     dim3(512),  dim3(256), 0, stream, x, w1, sup1);
    hipLaunchKernelGGL(k_packB1T, dim3(1280), dim3(256), 0, stream, sup1, y, B1T);
    hipLaunchKernelGGL(HIP_KERNEL_NAME(k_gemmF<64, 2, 2, 2, 5>), dim3(640), dim3(256), 0, stream,
                       adj, mask1, B1T, U, S1);
    hipLaunchKernelGGL(k_finC,    dim3(256),  dim3(256), 0, stream, U, S1, b1, h1, B2T);
    hipLaunchKernelGGL(k_hw2,     dim3(256),  dim3(256), 0, stream, h1, w2, B2T);
    hipLaunchKernelGGL(HIP_KERNEL_NAME(k_gemmF<96, 4, 1, 8, 1>), dim3(512), dim3(256), 0, stream,
                       adj, mask2, B2T, U, S2);
    hipLaunchKernelGGL(k_finD,    dim3(256),  dim3(256), 0, stream, U, S2, b2, out);
}

// Round 5
// 436.435 us; speedup vs baseline: 1.1304x; 1.1304x over previous
//
#include <hip/hip_runtime.h>
#include <cstdint>
#include <cstddef>

typedef float f32x4 __attribute__((ext_vector_type(4)));
typedef __bf16 bf16x8_t __attribute__((ext_vector_type(8)));
typedef short s16x8_t __attribute__((ext_vector_type(8)));
typedef unsigned short u16x4_t __attribute__((ext_vector_type(4)));

#define NN 8192   // nodes
#define FD 512    // in features
#define HD 256    // hidden
#define CD 40    // classes

static __device__ __forceinline__ unsigned short f2bf(float f) {
    unsigned int u = __builtin_bit_cast(unsigned int, f);
    u += 0x7FFFu + ((u >> 16) & 1u);          // round-to-nearest-even
    return (unsigned short)(u >> 16);
}
static __device__ __forceinline__ float bf2f(unsigned short s) {
    unsigned int u = ((unsigned int)s) << 16;
    return __builtin_bit_cast(float, u);
}

typedef __attribute__((address_space(3))) unsigned int lds_u32_t;
typedef __attribute__((address_space(1))) const unsigned int gbl_u32_t;
static __device__ __forceinline__ void gload16(const void* g, const void* lds) {
    __builtin_amdgcn_global_load_lds((gbl_u32_t*)g, (lds_u32_t*)lds, 16, 0, 0);
}

// ---------------- K-1: zero the rowsum accumulators ----------------
__global__ __launch_bounds__(256) void k_zero(float* __restrict__ S1,
                                              float* __restrict__ S2) {
    const int i = blockIdx.x * 256 + threadIdx.x;
    S1[i] = 0.f;
    S2[i] = 0.f;
}

// ---------------- K1: sup1 = x @ w1  (8192x512 @ 512x256, f32 vector) ----------------
__global__ __launch_bounds__(256) void k_xw1(const float* __restrict__ x,
                                             const float* __restrict__ w1,
                                             float* __restrict__ sup1) {
    __shared__ float xs[64][36];
    __shared__ float ws[32][68];
    const int m0 = (blockIdx.x >> 2) * 64;
    const int n0 = (blockIdx.x & 3) * 64;
    const int t = threadIdx.x;
    const int tx = t & 15, ty = t >> 4;
    float acc[4][4] = {};
    for (int k0 = 0; k0 < FD; k0 += 32) {
        for (int i = t; i < 512; i += 256) {
            int r = i >> 3, c = (i & 7) << 2;
            *(float4*)&xs[r][c] = *(const float4*)&x[(size_t)(m0 + r) * FD + k0 + c];
        }
        for (int i = t; i < 512; i += 256) {
            int r = i >> 4, c = (i & 15) << 2;
            *(float4*)&ws[r][c] = *(const float4*)&w1[(size_t)(k0 + r) * HD + n0 + c];
        }
        __syncthreads();
        for (int k = 0; k < 32; ++k) {
            float a_[4], b_[4];
            #pragma unroll
            for (int i = 0; i < 4; ++i) a_[i] = xs[ty * 4 + i][k];
            #pragma unroll
            for (int j = 0; j < 4; ++j) b_[j] = ws[k][tx * 4 + j];
            #pragma unroll
            for (int i = 0; i < 4; ++i)
                #pragma unroll
                for (int j = 0; j < 4; ++j) acc[i][j] += a_[i] * b_[j];
        }
        __syncthreads();
    }
    #pragma unroll
    for (int i = 0; i < 4; ++i)
        #pragma unroll
        for (int j = 0; j < 4; ++j)
            sup1[(size_t)(m0 + ty * 4 + i) * HD + n0 + tx * 4 + j] = acc[i][j];
}

// ---------------- K2: pack B1T[n][k] (bf16, 320 x 8192) = [sup1 | y | 0-pad]^T ----------------
__global__ __launch_bounds__(256) void k_packB1T(const float* __restrict__ sup1,
                                                 const float* __restrict__ y,
                                                 unsigned short* __restrict__ B1T) {
    __shared__ float tl[64][33];
    const int kt = blockIdx.x & 127;
    const int nt = blockIdx.x >> 7;
    const int k0 = kt * 64, n0 = nt * 32;
    const int t = threadIdx.x;
    {
        const int kr = t >> 2, cb = (t & 3) * 8;
        #pragma unroll
        for (int j = 0; j < 8; ++j) {
            const int n = n0 + cb + j;
            float v;
            if (n < 256)      v = sup1[(size_t)(k0 + kr) * HD + n];
            else if (n < 296) v = y[(size_t)(k0 + kr) * CD + (n - 256)];
            else              v = 0.f;
            tl[kr][cb + j] = v;
        }
    }
    __syncthreads();
    {
        const int nr = t >> 3, part = t & 7;
        unsigned short tmp[8];
        #pragma unroll
        for (int j = 0; j < 8; ++j) tmp[j] = f2bf(tl[part * 8 + j][nr]);
        *(s16x8_t*)&B1T[(size_t)(n0 + nr) * NN + k0 + part * 8] = *(s16x8_t*)tmp;
    }
}

// ---------------- K3: fused GEMM: A = bf16(adj .* mask) computed in-staging ----------------
// r4 post-mortem: at grid 640/512 the reg-staged A-path (load->mul->ds_write->barrier) is
// latency-bound (occupancy 17%, hbm 1.1 TB/s, all pipes idle). Fix = deeper split-K so
// 5 blocks/CU co-reside (20 waves/CU) and wave-level TLP hides the ~900cy HBM latency.
// MFMA core / fragments / C-epilogue identical to the verified k_gemm.
// For NTILES>1: XCD-grouping block remap (r3, measured win) so A-panel siblings share L2.
template<int BN, int WM, int WN, int SPLIT, int NTILES>
__global__ __launch_bounds__(256) void k_gemmF(const float* __restrict__ adj,
                                               const float* __restrict__ mask,
                                               const unsigned short* __restrict__ Bt,
                                               float* __restrict__ Cp,
                                               float* __restrict__ S) {
    constexpr int BM = 128, BK = 64;
    constexpr int MF = BM / (WM * 16);
    constexpr int NF = BN / (WN * 16);
    constexpr int NBI = BN / 32;          // B gload insts per wave
    constexpr int NSTR = NTILES * BN;     // Cp row stride
    constexpr int MT = NN / BM;           // 64 m-tiles
    __shared__ unsigned short As[BM * BK];
    __shared__ unsigned short Bs[BN * BK];
    int mt, ks, nt;
    if constexpr (NTILES > 1) {
        constexpr int NXCD = 8;
        constexpr int PAIRS = MT * SPLIT;              // (mt,ks) pairs
        static_assert(PAIRS % NXCD == 0, "pair count must split across XCDs");
        constexpr int PPX = PAIRS / NXCD;              // pairs per XCD
        const int L = blockIdx.x;
        const int x = L % NXCD, q = L / NXCD;          // XCD id, slot on that XCD
        const int pr = x * PPX + q / NTILES;           // pair index
        nt = q % NTILES;
        mt = pr / SPLIT;
        ks = pr % SPLIT;
    } else {
        int b = blockIdx.x;
        nt = 0;
        ks = b % SPLIT;  b /= SPLIT;
        mt = b;
    }
    const int m0 = mt * BM, n0 = nt * BN;
    const int t = threadIdx.x, w = t >> 6, ln = t & 63;
    const int wn = w % WN, wm = w / WN;
    const int lrow = ln & 15, lkq = ln >> 4;
    const int kbeg = ks * (NN / SPLIT), kend = kbeg + (NN / SPLIT);
    const bool dosum = (NTILES == 1) || (nt == 0);

    // A-staging: granule g = t + i*256 (i<8) -> local row r = g>>4, q16 = g&15
    // (16 f32x4 granules per 64-col row). 16 lanes cover one row's 256B contiguously
    // per matrix -> fully coalesced. LDS target keeps the XOR chunk swizzle:
    // chunk cg = q16>>1 stored at slot cg^(r&7), half (q16&1).
    float rsum[8] = {};
    f32x4 acc[MF][NF] = {};
    for (int kb = kbeg; kb < kend; kb += BK) {
        f32x4 av[8], mv[8];
        #pragma unroll
        for (int i = 0; i < 8; ++i) {
            const int g = t + i * 256;
            const int r = g >> 4, q16 = g & 15;
            const size_t goff = (size_t)(m0 + r) * NN + kb + q16 * 4;
            av[i] = *(const f32x4*)&adj[goff];
            mv[i] = *(const f32x4*)&mask[goff];
        }
        // B stage (BN*128 bytes, direct-to-LDS)
        #pragma unroll
        for (int i = 0; i < NBI; ++i) {
            const int off = (w * NBI + i) * 1024 + ln * 16;
            const int r = off >> 7, ch = (off >> 4) & 7;
            gload16(Bt + (size_t)(n0 + r) * NN + kb + ((ch ^ (r & 7)) << 3),
                    &Bs[(w * NBI + i) * 512]);
        }
        f32x4 pr8[8];
        #pragma unroll
        for (int i = 0; i < 8; ++i) {
            #pragma unroll
            for (int e = 0; e < 4; ++e) pr8[i][e] = av[i][e] * mv[i][e];
        }
        if (dosum) {
            #pragma unroll
            for (int i = 0; i < 8; ++i)
                rsum[i] += fabsf(pr8[i][0]) + fabsf(pr8[i][1]) + fabsf(pr8[i][2]) + fabsf(pr8[i][3]);
        }
        #pragma unroll
        for (int i = 0; i < 8; ++i) {
            const int g = t + i * 256;
            const int r = g >> 4, q16 = g & 15;
            u16x4_t pk;
            pk.x = f2bf(pr8[i][0]); pk.y = f2bf(pr8[i][1]);
            pk.z = f2bf(pr8[i][2]); pk.w = f2bf(pr8[i][3]);
            *(u16x4_t*)&As[r * 64 + (((q16 >> 1) ^ (r & 7)) << 3) + ((q16 & 1) << 2)] = pk;
        }
        __syncthreads();   // drains vmcnt (gload_lds) + lgkmcnt (ds_write)

        bf16x8_t af[MF][2];
        #pragma unroll
        for (int mf = 0; mf < MF; ++mf)
            #pragma unroll
            for (int kh = 0; kh < 2; ++kh) {
                const int r = wm * (MF * 16) + mf * 16 + lrow;
                const int ch = (kh * 4 + lkq) ^ (r & 7);
                af[mf][kh] = __builtin_bit_cast(bf16x8_t, *(const s16x8_t*)&As[r * 64 + ch * 8]);
            }
        bf16x8_t bfr[NF][2];
        #pragma unroll
        for (int nf = 0; nf < NF; ++nf)
            #pragma unroll
            for (int kh = 0; kh < 2; ++kh) {
                const int r = wn * (NF * 16) + nf * 16 + lrow;
                const int ch = (kh * 4 + lkq) ^ (r & 7);
                bfr[nf][kh] = __builtin_bit_cast(bf16x8_t, *(const s16x8_t*)&Bs[r * 64 + ch * 8]);
            }
        #pragma unroll
        for (int kh = 0; kh < 2; ++kh)
            #pragma unroll
            for (int mf = 0; mf < MF; ++mf)
                #pragma unroll
                for (int nf = 0; nf < NF; ++nf)
                    acc[mf][nf] = __builtin_amdgcn_mfma_f32_16x16x32_bf16(
                        af[mf][kh], bfr[nf][kh], acc[mf][nf], 0, 0, 0);
        __syncthreads();
    }
    // epilogue: partial f32 store. C/D layout: col = lane&15 (from Bt row), row = (lane>>4)*4+e (from A row)
    #pragma unroll
    for (int mf = 0; mf < MF; ++mf)
        #pragma unroll
        for (int nf = 0; nf < NF; ++nf)
            #pragma unroll
            for (int e = 0; e < 4; ++e) {
                const int m = m0 + wm * (MF * 16) + mf * 16 + lkq * 4 + e;
                const int n = n0 + wn * (NF * 16) + nf * 16 + lrow;
                Cp[((size_t)ks * NN + m) * NSTR + n] = acc[mf][nf][e];
            }
    // rowsum commit: thread's granule rows are r(i) = w*4 + (ln>>4) + i*16;
    // 16 lanes (same ln>>4 group) share each row -> xor-reduce 1,2,4,8 then one atomic.
    if (dosum) {
        #pragma unroll
        for (int i = 0; i < 8; ++i) {
            float v = rsum[i];
            v += __shfl_xor(v, 1, 64);
            v += __shfl_xor(v, 2, 64);
            v += __shfl_xor(v, 4, 64);
            v += __shfl_xor(v, 8, 64);
            if ((ln & 15) == 0)
                atomicAdd(&S[m0 + w * 4 + (ln >> 4) + i * 16], v);
        }
    }
}

// ---------------- K4: finC — U1 = sum(4 Uc parts)/rowsum; h1 = relu(+b1) bf16; yh1 -> B2T rows 40..79 ----------------
__global__ __launch_bounds__(256) void k_finC(const float* __restrict__ U,   // [4][NN][320]
                                              const float* __restrict__ S1,  // raw rowsums
                                              const float* __restrict__ b1,
                                              unsigned short* __restrict__ h1,
                                              unsigned short* __restrict__ B2T) {
    const int t = threadIdx.x;
    const int r = t >> 3, l8 = t & 7;
    const int m = blockIdx.x * 32 + r;
    const float si = 1.0f / fmaxf(S1[m], 1e-12f);
    #pragma unroll
    for (int i = 0; i < 10; ++i) {
        const int c = (l8 + i * 8) * 4;       // 0..316
        f32x4 v = {};
        #pragma unroll
        for (int p = 0; p < 4; ++p) {
            f32x4 a = *(const f32x4*)&U[((size_t)p * NN + m) * 320 + c];
            #pragma unroll
            for (int e = 0; e < 4; ++e) v[e] += a[e];
        }
        #pragma unroll
        for (int e = 0; e < 4; ++e) v[e] *= si;
        if (i < 8) {                           // c < 256: hidden part
            u16x4_t pk;
            #pragma unroll
            for (int e = 0; e < 4; ++e) {
                const float hv = fmaxf(v[e] + b1[c + e], 0.f);
                ((unsigned short*)&pk)[e] = f2bf(hv);
            }
            *(u16x4_t*)&h1[(size_t)m * HD + c] = pk;
        } else {                               // c in 256..316: y_hat part
            #pragma unroll
            for (int e = 0; e < 4; ++e) {
                const int cc = c + e;
                if (cc < 296) B2T[(size_t)(40 + cc - 256) * NN + m] = f2bf(v[e]);
            }
        }
    }
}

// ---------------- K5: support2 = h1 @ w2 -> B2T rows 0..39 (transposed bf16); zero rows 80..95 ----------------
__global__ __launch_bounds__(256) void k_hw2(const unsigned short* __restrict__ h1,
                                             const float* __restrict__ w2,
                                             unsigned short* __restrict__ B2T) {
    __shared__ float w2s[HD * CD];
    __shared__ unsigned short h1s[32][264];
    __shared__ float ot[CD][33];
    const int t = threadIdx.x;
    const int mb = blockIdx.x * 32;
    for (int i = t; i < HD * CD; i += 256) w2s[i] = w2[i];
    for (int i = t; i < 1024; i += 256) {
        const int r = i >> 5, c = (i & 31) * 8;
        *(s16x8_t*)&h1s[r][c] = *(const s16x8_t*)&h1[(size_t)(mb + r) * HD + c];
    }
    __syncthreads();
    const int m = t >> 3, n0 = t & 7;
    float a5[5] = {};
    for (int k = 0; k < HD; ++k) {
        const float hv = bf2f(h1s[m][k]);
        #pragma unroll
        for (int j = 0; j < 5; ++j) a5[j] += hv * w2s[k * CD + n0 + 8 * j];
    }
    #pragma unroll
    for (int j = 0; j < 5; ++j) ot[n0 + 8 * j][m] = a5[j];
    __syncthreads();
    for (int i = t; i < CD * 32; i += 256) {
        const int n = i >> 5, mm = i & 31;
        B2T[(size_t)n * NN + mb + mm] = f2bf(ot[n][mm]);
    }
    for (int i = t; i < 16 * 32; i += 256)    // zero pad rows 80..95
        B2T[(size_t)(80 + (i >> 5)) * NN + mb + (i & 31)] = 0;
}

// ---------------- K6: finD — sum 16 partials, /rowsum, +b2, log_softmax both mats, store ----------------
__global__ __launch_bounds__(256) void k_finD(const float* __restrict__ U,   // [16][NN][96]
                                              const float* __restrict__ S2,  // raw rowsums
                                              const float* __restrict__ b2,
                                              float* __restrict__ out) {
    __shared__ float vt[32][100];
    const int t = threadIdx.x;
    const int mb = blockIdx.x * 32;
    for (int i = t; i < 32 * 24; i += 256) {
        const int r = i / 24, f4 = i % 24;
        const int m = mb + r;
        f32x4 s = {};
        #pragma unroll
        for (int p = 0; p < 16; ++p) {
            f32x4 v = *(const f32x4*)&U[((size_t)p * NN + m) * 96 + f4 * 4];
            #pragma unroll
            for (int e = 0; e < 4; ++e) s[e] += v[e];
        }
        const float si = 1.0f / fmaxf(S2[m], 1e-12f);
        #pragma unroll
        for (int e = 0; e < 4; ++e) {
            const int c = f4 * 4 + e;
            float v = s[e] * si;
            if (c < CD) v += b2[c];
            vt[r][c] = v;
        }
    }
    __syncthreads();
    const int l8 = t & 7;
    #pragma unroll
    for (int pass = 0; pass < 2; ++pass) {
        const int task = pass * 32 + (t >> 3);
        const int row = task & 31, mat = task >> 5;
        float vals[5];
        float mx = -3.0e38f;
        #pragma unroll
        for (int j = 0; j < 5; ++j) { vals[j] = vt[row][mat * CD + l8 + 8 * j]; mx = fmaxf(mx, vals[j]); }
        mx = fmaxf(mx, __shfl_xor(mx, 4, 8));
        mx = fmaxf(mx, __shfl_xor(mx, 2, 8));
        mx = fmaxf(mx, __shfl_xor(mx, 1, 8));
        float se = 0.f;
        #pragma unroll
        for (int j = 0; j < 5; ++j) se += expf(vals[j] - mx);
        se += __shfl_xor(se, 4, 8);
        se += __shfl_xor(se, 2, 8);
        se += __shfl_xor(se, 1, 8);
        const float ls = logf(se);
        float* op = out + (size_t)mat * (NN * CD) + (size_t)(mb + row) * CD;
        #pragma unroll
        for (int j = 0; j < 5; ++j) op[l8 + 8 * j] = vals[j] - mx - ls;
    }
}

extern "C" void kernel_launch(void* const* d_in, const int* in_sizes, int n_in,
                              void* d_out, int out_size, void* d_ws, size_t ws_size,
                              hipStream_t stream) {
    (void)in_sizes; (void)n_in; (void)out_size; (void)ws_size;
    const float* x     = (const float*)d_in[0];
    const float* adj   = (const float*)d_in[1];
    const float* y     = (const float*)d_in[2];
    const float* mask1 = (const float*)d_in[3];
    const float* mask2 = (const float*)d_in[4];
    const float* w1    = (const float*)d_in[5];
    const float* b1    = (const float*)d_in[6];
    const float* w2    = (const float*)d_in[7];
    const float* b2    = (const float*)d_in[8];
    float* out = (float*)d_out;

    char* p = (char*)d_ws;
    float*          sup1 = (float*)p;          p += 8388608;    // 8192x256 f32
    unsigned short* B1T  = (unsigned short*)p; p += 5242880;    // 320x8192 bf16
    unsigned short* h1   = (unsigned short*)p; p += 4194304;    // 8192x256 bf16
    unsigned short* B2T  = (unsigned short*)p; p += 1572864;    // 96x8192 bf16
    float*          U    = (float*)p;          p += 50331648;   // overlay: Uc[4][8192][320] (40MB) / Ud[16][8192][96] (48MB)
    float*          S1   = (float*)p;          p += 32768;      // raw rowsums |adj.*mask1|
    float*          S2   = (float*)p;          p += 32768;      // raw rowsums |adj.*mask2|

    hipLaunchKernelGGL(k_zero,    dim3(32),   dim3(256), 0, stream, S1, S2);
    hipLaunchKernelGGL(k_xw1,     dim3(512),  dim3(256), 0, stream, x, w1, sup1);
    hipLaunchKernelGGL(k_packB1T, dim3(1280), dim3(256), 0, stream, sup1, y, B1T);
    hipLaunchKernelGGL(HIP_KERNEL_NAME(k_gemmF<64, 2, 2, 4, 5>), dim3(1280), dim3(256), 0, stream,
                       adj, mask1, B1T, U, S1);
    hipLaunchKernelGGL(k_finC,    dim3(256),  dim3(256), 0, stream, U, S1, b1, h1, B2T);
    hipLaunchKernelGGL(k_hw2,     dim3(256),  dim3(256), 0, stream, h1, w2, B2T);
    hipLaunchKernelGGL(HIP_KERNEL_NAME(k_gemmF<96, 4, 1, 16, 1>), dim3(1024), dim3(256), 0, stream,
                       adj, mask2, B2T, U, S2);
    hipLaunchKernelGGL(k_finD,    dim3(256),  dim3(256), 0, stream, U, S2, b2, out);
}